// Round 4
// baseline (1429.902 us; speedup 1.0000x reference)
//
#include <hip/hip_runtime.h>
#include <hip/hip_bf16.h>

// Problem constants (from reference config)
#define CIN 256
#define COUT 256
#define HW 56
#define BATCH 8
#define L_SPATIAL 3136            // 56*56
#define K_TOTAL 2304              // CIN*3*3
#define NT 36                     // K chunks of 64
#define NH 18                     // n-chunks retained per wave (half)
#define ROWF (COUT * NT)          // 9216 floats per (b,l) row of psum
#define KSTRIDE 2312              // bf16 elems per m-row in LDS (+8 pad)
#define ATILE_BYTES (16 * KSTRIDE * 2)   // 73,984 B; stage (2x36,864=73,728) aliases it
#define LDS_BYTES ATILE_BYTES            // 74 KB -> 2 WG/CU
#define MT_TOTAL 1568             // m-tiles (8*3136/16)
#define TILES_PER_IMG 196
#define QMAXF 127.0f
#define QMINF -128.0f

typedef short bf16x8 __attribute__((ext_vector_type(8)));
typedef float f32x4 __attribute__((ext_vector_type(4)));

__device__ __forceinline__ void nt_store4(float* p, f32x4 v) {
  __builtin_nontemporal_store(v, reinterpret_cast<f32x4*>(p));
}

// ---- prep: Bsign[c][k] = sign(w) as bf16 (B^T layout = MFMA B-frag order), scale[c] = mean|w| ----
__global__ __launch_bounds__(256) void prep_kernel(
    const float* __restrict__ w, unsigned short* __restrict__ bsign,
    float* __restrict__ scale) {
  const int c = blockIdx.x;
  const int t = threadIdx.x;
  const float* row = w + (size_t)c * K_TOTAL;
  unsigned short* out = bsign + (size_t)c * K_TOTAL;
  float acc = 0.0f;
#pragma unroll
  for (int j = 0; j < 9; ++j) {
    const int k = t + 256 * j;
    const float v = row[k];
    acc += __builtin_fabsf(v);
    out[k] = (v > 0.0f) ? (unsigned short)0x3F80
           : ((v < 0.0f) ? (unsigned short)0xBF80 : (unsigned short)0);
  }
#pragma unroll
  for (int o = 32; o > 0; o >>= 1) acc += __shfl_down(acc, o, 64);
  __shared__ float red[4];
  if ((t & 63) == 0) red[t >> 6] = acc;
  __syncthreads();
  if (t == 0) scale[c] = (red[0] + red[1] + red[2] + red[3]) * (1.0f / 2304.0f);
}

// Compute all 36 K-chunks (full saturating scan), retain chunks [H*18, H*18+18)
// in ps[]. H is a template arg so every ps index is compile-time (rule #20).
template <int H>
__device__ __forceinline__ void compute_half(
    const unsigned short* __restrict__ aptr,
    const unsigned short* __restrict__ bptr,
    f32x4* __restrict__ ps, f32x4& sacc) {
  const f32x4 zero = {0.0f, 0.0f, 0.0f, 0.0f};
  bf16x8 b0 = *reinterpret_cast<const bf16x8*>(bptr);
  bf16x8 b1 = *reinterpret_cast<const bf16x8*>(bptr + 32);
#pragma unroll
  for (int n = 0; n < NT; ++n) {
    bf16x8 nb0, nb1;
    if (n + 1 < NT) {                     // prefetch next B-frag
      nb0 = *reinterpret_cast<const bf16x8*>(bptr + (n + 1) * 64);
      nb1 = *reinterpret_cast<const bf16x8*>(bptr + (n + 1) * 64 + 32);
    }
    bf16x8 a0 = *reinterpret_cast<const bf16x8*>(aptr + n * 64);
    bf16x8 a1 = *reinterpret_cast<const bf16x8*>(aptr + n * 64 + 32);
    f32x4 acc = __builtin_amdgcn_mfma_f32_16x16x32_bf16(a0, b0, zero, 0, 0, 0);
    acc = __builtin_amdgcn_mfma_f32_16x16x32_bf16(a1, b1, acc, 0, 0, 0);
    if (n >= H * NH && n < (H + 1) * NH) ps[n - H * NH] = acc;  // compile-time idx
    if (n == 0) {
      sacc = acc;                         // scan carry starts UNCLIPPED (matches ref)
    } else {
#pragma unroll
      for (int e = 0; e < 4; ++e)
        sacc[e] = __builtin_amdgcn_fmed3f(sacc[e] + acc[e], QMINF, QMAXF);
    }
    b0 = nb0;
    b1 = nb1;
  }
}

// ---- main: WG = 16 m-rows x 64 couts, 8 waves = 4 c-subtiles x 2 n-halves.
// Each wave computes all 36 chunks (redundant MFMA is ~free) but retains only 18
// -> ps[18] = 72 VGPR -> 4 waves/SIMD; LDS = A-tile only (stage aliases dead A)
// -> 2 WG/CU. 16 waves/CU vs previous 8: phases finally overlap.
__global__ __launch_bounds__(512, 4) void satconv_kernel(
    const float* __restrict__ x, const unsigned short* __restrict__ bsign,
    const float* __restrict__ scale, float* __restrict__ y_out,
    float* __restrict__ psum_out) {
  extern __shared__ char smem[];
  unsigned short* Atile = (unsigned short*)smem;   // [16][KSTRIDE] bf16
  float* stage = (float*)smem;                     // aliases A after compute barrier

  const int tid = threadIdx.x;
  const int bid = blockIdx.x;
  const int mt = bid % MT_TOTAL;                   // cb in HIGH bits: bid%8 == mt%8,
  const int cb = bid / MT_TOTAL;                   // per-image XCD swizzle preserved
  const int m_tile = (mt & 7) * TILES_PER_IMG + (mt >> 3);
  const int m0 = m_tile << 4;

  // ---------- build A tile: lanes 0-15 = consecutive m (= consecutive ow) ----------
  {
    const int ml = tid & 15;
    const int grp = tid >> 4;                 // 0..31
    const int m = m0 + ml;
    const int b = m / L_SPATIAL;
    const int l = m - b * L_SPATIAL;
    const int oh = l / HW;
    const int ow = l - oh * HW;
    const float* xb = x + (size_t)b * (CIN * L_SPATIAL);
    unsigned short* arow = Atile + ml * KSTRIDE;
    for (int r = grp; r < 768; r += 32) {     // r = ci*3 + kh
      const int ci = r / 3;
      const int kh = r - ci * 3;
      const int h = oh + kh - 1;
      const bool hv = ((unsigned)h < (unsigned)HW);
      const float* xr = xb + (ci * HW + h) * HW;
      const int kb = ci * 9 + kh * 3;
#pragma unroll
      for (int kw = 0; kw < 3; ++kw) {
        const int wv = ow + kw - 1;
        float v = 0.0f;
        if (hv && ((unsigned)wv < (unsigned)HW)) v = xr[wv];
        __hip_bfloat16 bv = __float2bfloat16(v);
        arow[kb + kw] = *reinterpret_cast<unsigned short*>(&bv);
      }
    }
  }

  const int lane = tid & 63;
  const int wave = tid >> 6;                  // 0..7
  const int cl = lane & 15;
  const int q = lane >> 4;
  const int cs = wave >> 1;                   // 0..3: c-subtile of 16
  const int h = wave & 1;                     // n-half
  const int c = (cb << 6) + (cs << 4) + cl;

  const float sc = scale[c];                  // used by h==0 for y

  __syncthreads();

  const unsigned short* aptr = Atile + cl * KSTRIDE + q * 8;
  const unsigned short* bptr = bsign + (size_t)c * K_TOTAL + q * 8;
  const int b_img = m0 / L_SPATIAL;           // WG never crosses batch boundary
  const int l0 = m0 - b_img * L_SPATIAL;

  f32x4 ps[NH];
  f32x4 sacc;
  if (h == 0) compute_half<0>(aptr, bptr, ps, sacc);
  else        compute_half<1>(aptr, bptr, ps, sacc);

  // ---- y: frag (cl,q,e) = (c, m0+4q+e); m-inner layout -> direct dense store ----
  if (h == 0) {
    f32x4 yv;
#pragma unroll
    for (int e = 0; e < 4; ++e) yv[e] = sacc[e] * sc;
    nt_store4(y_out + ((size_t)b_img * COUT + c) * L_SPATIAL + l0 + (q << 2), yv);
  }

  __syncthreads();                            // all A-tile reads done; stage may clobber

  // ---- psum: 2 rounds; round r stages c-subtiles {2r,2r+1} into A-space, then
  // all 8 waves copy out as dense 1KB NT stores (full n-rows, no amplification).
#pragma unroll
  for (int r = 0; r < 2; ++r) {
    if ((cs >> 1) == r) {
      // region layout: [cs&1][m 0..15][576] where 576 = 16c*36n (c-local, n inner)
      float* reg = stage + (cs & 1) * 9216;
      const int coldw = cl * 36 + h * NH;
#pragma unroll
      for (int j = 0; j < NH; ++j) {
#pragma unroll
        for (int e = 0; e < 4; ++e)
          reg[((q << 2) + e) * 576 + coldw + j] = ps[j][e];
      }
    }
    __syncthreads();
    // copy: wave w owns region CS=w>>2, m-rows 4*(w&3)..+3 => flat LDS w*2304 + x
    {
      const int CS = wave >> 2;
      const int mrow0 = (wave & 3) << 2;
      const int cs_g = (r << 1) + CS;
      const float* lds_f = stage + wave * 2304;
      float* gbase = psum_out + (size_t)(m0 + mrow0) * ROWF
                   + ((cb << 6) + (cs_g << 4)) * 36;
#pragma unroll
      for (int i = 0; i < 9; ++i) {
        const int xx = i * 256 + (lane << 2);
        const int ml = xx / 576;              // 0..3 (magic-mul)
        const int roff = xx - ml * 576;
        f32x4 v = *reinterpret_cast<const f32x4*>(lds_f + xx);
        nt_store4(gbase + (size_t)ml * ROWF + roff, v);
      }
    }
    __syncthreads();
  }
}

extern "C" void kernel_launch(void* const* d_in, const int* in_sizes, int n_in,
                              void* d_out, int out_size, void* d_ws, size_t ws_size,
                              hipStream_t stream) {
  const float* x = (const float*)d_in[0];
  const float* w = (const float*)d_in[1];
  float* y = (float*)d_out;
  float* psum = y + (size_t)BATCH * COUT * L_SPATIAL;            // y is 6,422,528 floats
  unsigned short* bsign = (unsigned short*)d_ws;                 // 256*2304*2 = 1,179,648 B
  float* scale = (float*)((char*)d_ws + (size_t)COUT * K_TOTAL * 2);

  prep_kernel<<<COUT, 256, 0, stream>>>(w, bsign, scale);

  hipFuncSetAttribute(reinterpret_cast<const void*>(satconv_kernel),
                      hipFuncAttributeMaxDynamicSharedMemorySize, LDS_BYTES);
  satconv_kernel<<<MT_TOTAL * 4, 512, LDS_BYTES, stream>>>(
      x, bsign, scale, y, psum);
}

// Round 5
// 1196.084 us; speedup vs baseline: 1.1955x; 1.1955x over previous
//
#include <hip/hip_runtime.h>
#include <hip/hip_bf16.h>

// Problem constants (from reference config)
#define CIN 256
#define COUT 256
#define HW 56
#define BATCH 8
#define L_SPATIAL 3136            // 56*56
#define K_TOTAL 2304              // CIN*3*3
#define NT 36                     // K chunks of 64
#define NH 18                     // n-chunks retained per wave (half)
#define ROWF (COUT * NT)          // 9216 floats per (b,l) row of psum
#define KSTRIDE 2312              // bf16 elems per m-row in LDS (+8 pad)
#define ATILE_BYTES (16 * KSTRIDE * 2)       // 73,984 B
#define STAGE_OFF ATILE_BYTES                // stage: 8 pairs x 2304 f32 = 73,728 B
#define CARRY_OFF (ATILE_BYTES + 73728)      // carry: 2048 f32 = 8,192 B
#define LDS_BYTES (CARRY_OFF + 8192)         // 155,904 B <= 160 KiB -> 1 WG/CU, 16 waves
#define MT_TOTAL 1568             // m-tiles (8*3136/16)
#define TILES_PER_IMG 196
#define QMAXF 127.0f
#define QMINF -128.0f

typedef short bf16x8 __attribute__((ext_vector_type(8)));
typedef float f32x4 __attribute__((ext_vector_type(4)));
typedef float f32x2 __attribute__((ext_vector_type(2)));

__device__ __forceinline__ void nt_store4(float* p, f32x4 v) {
  __builtin_nontemporal_store(v, reinterpret_cast<f32x4*>(p));
}

// ---- prep: Bsign[c][k] = sign(w) as bf16 (B^T layout = MFMA B-frag order), scale[c] = mean|w| ----
__global__ __launch_bounds__(256) void prep_kernel(
    const float* __restrict__ w, unsigned short* __restrict__ bsign,
    float* __restrict__ scale) {
  const int c = blockIdx.x;
  const int t = threadIdx.x;
  const float* row = w + (size_t)c * K_TOTAL;
  unsigned short* out = bsign + (size_t)c * K_TOTAL;
  float acc = 0.0f;
#pragma unroll
  for (int j = 0; j < 9; ++j) {
    const int k = t + 256 * j;
    const float v = row[k];
    acc += __builtin_fabsf(v);
    out[k] = (v > 0.0f) ? (unsigned short)0x3F80
           : ((v < 0.0f) ? (unsigned short)0xBF80 : (unsigned short)0);
  }
#pragma unroll
  for (int o = 32; o > 0; o >>= 1) acc += __shfl_down(acc, o, 64);
  __shared__ float red[4];
  if ((t & 63) == 0) red[t >> 6] = acc;
  __syncthreads();
  if (t == 0) scale[c] = (red[0] + red[1] + red[2] + red[3]) * (1.0f / 2304.0f);
}

// Compute 18 chunks [H*18, H*18+18), retain all in ps[]; H==0 also runs the
// saturating scan prefix (carry starts UNCLIPPED at chunk 0, matching ref).
template <int H>
__device__ __forceinline__ void compute18(
    const unsigned short* __restrict__ aptr,
    const unsigned short* __restrict__ bptr,
    f32x4* __restrict__ ps, f32x4& sacc) {
  const f32x4 zero = {0.0f, 0.0f, 0.0f, 0.0f};
  const unsigned short* ap = aptr + H * NH * 64;
  const unsigned short* bp = bptr + H * NH * 64;
  bf16x8 b0 = *reinterpret_cast<const bf16x8*>(bp);
  bf16x8 b1 = *reinterpret_cast<const bf16x8*>(bp + 32);
#pragma unroll
  for (int j = 0; j < NH; ++j) {
    bf16x8 nb0, nb1;
    if (j + 1 < NH) {                     // prefetch next B-frag
      nb0 = *reinterpret_cast<const bf16x8*>(bp + (j + 1) * 64);
      nb1 = *reinterpret_cast<const bf16x8*>(bp + (j + 1) * 64 + 32);
    }
    bf16x8 a0 = *reinterpret_cast<const bf16x8*>(ap + j * 64);
    bf16x8 a1 = *reinterpret_cast<const bf16x8*>(ap + j * 64 + 32);
    f32x4 acc = __builtin_amdgcn_mfma_f32_16x16x32_bf16(a0, b0, zero, 0, 0, 0);
    acc = __builtin_amdgcn_mfma_f32_16x16x32_bf16(a1, b1, acc, 0, 0, 0);
    ps[j] = acc;
    if (H == 0) {
      if (j == 0) {
        sacc = acc;
      } else {
#pragma unroll
        for (int e = 0; e < 4; ++e)
          sacc[e] = __builtin_amdgcn_fmed3f(sacc[e] + acc[e], QMINF, QMAXF);
      }
    }
    b0 = nb0;
    b1 = nb1;
  }
}

// ---- main: 1024 threads = 16 waves = 8 c-subtile pairs x 2 n-halves; 2 s-passes
// cover 256 couts. 1x total MFMA/A-build (vs R4's 2x/4x) at 16 waves/CU.
// Saturating scan split n-wise: h0 scans 0..17, hands carry via LDS; h1 stitches
// 18 fmed3 steps and stores y. Drain: R0's proven per-pair staged dense pattern.
__global__ __launch_bounds__(1024, 4) void satconv_kernel(
    const float* __restrict__ x, const unsigned short* __restrict__ bsign,
    const float* __restrict__ scale, float* __restrict__ y_out,
    float* __restrict__ psum_out) {
  extern __shared__ char smem[];
  unsigned short* Atile = (unsigned short*)smem;        // [16][KSTRIDE] bf16
  float* stage = (float*)(smem + STAGE_OFF);            // [8 pairs][2304] f32
  float* carryb = (float*)(smem + CARRY_OFF);           // [8][256] f32

  const int tid = threadIdx.x;
  const int bid = blockIdx.x;
  // XCD swizzle: 8 XCDs x 196 tiles; each XCD owns one batch image.
  const int m_tile = (bid & 7) * TILES_PER_IMG + (bid >> 3);
  const int m0 = m_tile << 4;

  // ---------- build A tile: lanes 0-15 = consecutive m (= consecutive ow) ----------
  {
    const int ml = tid & 15;
    const int grp = tid >> 4;                 // 0..63
    const int m = m0 + ml;
    const int b = m / L_SPATIAL;
    const int l = m - b * L_SPATIAL;
    const int oh = l / HW;
    const int ow = l - oh * HW;
    const float* xb = x + (size_t)b * (CIN * L_SPATIAL);
    unsigned short* arow = Atile + ml * KSTRIDE;
    for (int r = grp; r < 768; r += 64) {     // r = ci*3 + kh; 12 iters
      const int ci = r / 3;
      const int kh = r - ci * 3;
      const int hh = oh + kh - 1;
      const bool hv = ((unsigned)hh < (unsigned)HW);
      const float* xr = xb + (ci * HW + hh) * HW;
      const int kb = ci * 9 + kh * 3;
#pragma unroll
      for (int kw = 0; kw < 3; ++kw) {
        const int wv = ow + kw - 1;
        float v = 0.0f;
        if (hv && ((unsigned)wv < (unsigned)HW)) v = xr[wv];
        __hip_bfloat16 bv = __float2bfloat16(v);
        arow[kb + kw] = *reinterpret_cast<unsigned short*>(&bv);
      }
    }
  }

  const int lane = tid & 63;
  const int wave = tid >> 6;                  // 0..15
  const int cl = lane & 15;
  const int q = lane >> 4;
  const int cs = wave >> 1;                   // 0..7: c-subtile pair id
  const int h = wave & 1;                     // n-half

  // hoist scalar loads before the store streams
  const float sc_s0 = scale[cs * 16 + cl];
  const float sc_s1 = scale[128 + cs * 16 + cl];

  // precompute store-phase indices (R0 decode: f -> (qq, ci, n0))
  int base_it[9];
  {
#pragma unroll
    for (int it = 0; it < 9; ++it) {
      const int f = it * 256 + lane * 4;
      const int qq = f / 576;
      const int rem = f - qq * 576;
      const int ci = rem / 36;
      const int n0 = rem - ci * 36;
      base_it[it] = ((m0 + (qq << 2)) * COUT + ci) * NT + n0;
    }
  }

  __syncthreads();

  const unsigned short* aptr = Atile + cl * KSTRIDE + q * 8;
  const int b_img = m0 / L_SPATIAL;           // WG never crosses batch boundary
  const int l0 = m0 - b_img * L_SPATIAL;
  float* reg = stage + cs * 2304;             // per-pair staging region

  for (int s = 0; s < 2; ++s) {
    const int csub0 = (s << 7) + (cs << 4);   // c-subtile base (0..240)
    const int c = csub0 + cl;
    const unsigned short* bptr = bsign + (size_t)c * K_TOTAL + q * 8;

    f32x4 ps[NH];
    f32x4 sacc = {0.0f, 0.0f, 0.0f, 0.0f};
    if (h == 0) compute18<0>(aptr, bptr, ps, sacc);
    else        compute18<1>(aptr, bptr, ps, sacc);

    // ---- carry hand-off: h0 -> h1 (per (cs, cl, q), f32x4 over the 4 m's) ----
    if (h == 0)
      *reinterpret_cast<f32x4*>(carryb + cs * 256 + lane * 4) = sacc;
    __syncthreads();
    if (h == 1) {
      f32x4 cin = *reinterpret_cast<const f32x4*>(carryb + cs * 256 + lane * 4);
#pragma unroll
      for (int j = 0; j < NH; ++j) {
#pragma unroll
        for (int e = 0; e < 4; ++e)
          cin[e] = __builtin_amdgcn_fmed3f(cin[e] + ps[j][e], QMINF, QMAXF);
      }
      const float sc = (s == 0) ? sc_s0 : sc_s1;
      f32x4 yv;
#pragma unroll
      for (int e = 0; e < 4; ++e) yv[e] = cin[e] * sc;
      nt_store4(y_out + ((size_t)b_img * COUT + c) * L_SPATIAL + l0 + (q << 2), yv);
    }

    // ---- psum drain: 4 rg rounds; pair stages [q][16c][36n] (2304 f32), then
    // both waves copy out dense full-line NT stores (h0: it 0-4, h1: it 5-8).
    const int soff = csub0 * NT;
#pragma unroll
    for (int rg = 0; rg < 4; ++rg) {
      {
        // writer: 18 floats at reg[q*576 + cl*36 + h*18], vectorized b128/b64
        float* wr = reg + q * 576 + cl * 36 + h * NH;
        if (h == 0) {
          // base byte cl*144 + q*2304: 16B-aligned
          f32x4 v;
#pragma unroll
          for (int g = 0; g < 4; ++g) {
            v[0] = ps[4 * g + 0][rg]; v[1] = ps[4 * g + 1][rg];
            v[2] = ps[4 * g + 2][rg]; v[3] = ps[4 * g + 3][rg];
            *reinterpret_cast<f32x4*>(wr + 4 * g) = v;
          }
          f32x2 t = {ps[16][rg], ps[17][rg]};
          *reinterpret_cast<f32x2*>(wr + 16) = t;
        } else {
          // base byte ...+72: 8B-aligned; f32x2 then 4x f32x4 (16B-aligned)
          f32x2 t = {ps[0][rg], ps[1][rg]};
          *reinterpret_cast<f32x2*>(wr) = t;
          f32x4 v;
#pragma unroll
          for (int g = 0; g < 4; ++g) {
            v[0] = ps[4 * g + 2][rg]; v[1] = ps[4 * g + 3][rg];
            v[2] = ps[4 * g + 4][rg]; v[3] = ps[4 * g + 5][rg];
            *reinterpret_cast<f32x4*>(wr + 2 + 4 * g) = v;
          }
        }
      }
      __syncthreads();
      {
        const int rgoff = rg * ROWF + soff;
        const int it0 = (h == 0) ? 0 : 5;
        const int it1 = (h == 0) ? 5 : 9;
        for (int it = it0; it < it1; ++it) {
          f32x4 v = *reinterpret_cast<const f32x4*>(reg + it * 256 + lane * 4);
          nt_store4(psum_out + (size_t)(base_it[it] + rgoff), v);
        }
      }
      __syncthreads();
    }
  }
}

extern "C" void kernel_launch(void* const* d_in, const int* in_sizes, int n_in,
                              void* d_out, int out_size, void* d_ws, size_t ws_size,
                              hipStream_t stream) {
  const float* x = (const float*)d_in[0];
  const float* w = (const float*)d_in[1];
  float* y = (float*)d_out;
  float* psum = y + (size_t)BATCH * COUT * L_SPATIAL;            // y is 6,422,528 floats
  unsigned short* bsign = (unsigned short*)d_ws;                 // 256*2304*2 = 1,179,648 B
  float* scale = (float*)((char*)d_ws + (size_t)COUT * K_TOTAL * 2);

  prep_kernel<<<COUT, 256, 0, stream>>>(w, bsign, scale);

  hipFuncSetAttribute(reinterpret_cast<const void*>(satconv_kernel),
                      hipFuncAttributeMaxDynamicSharedMemorySize, LDS_BYTES);
  satconv_kernel<<<MT_TOTAL, 1024, LDS_BYTES, stream>>>(
      x, bsign, scale, y, psum);
}